// Round 5
// baseline (611.277 us; speedup 1.0000x reference)
//
#include <hip/hip_runtime.h>

#define N_NODES 50000
#define N_HEDGES 5000
#define NNZ 800000
#define IN_C 128
#define D1 256
#define D2 64

typedef unsigned int u32;
typedef unsigned short u16;

// ---- bf16 helpers: storage bf16, math f32 ----
__device__ __forceinline__ float bf_lo(u32 u) { return __uint_as_float(u << 16); }
__device__ __forceinline__ float bf_hi(u32 u) { return __uint_as_float(u & 0xffff0000u); }
__device__ __forceinline__ u32 rne16(float f) {
    u32 u = __float_as_uint(f);
    return (u + 0x7fffu + ((u >> 16) & 1u)) >> 16;
}
__device__ __forceinline__ u32 pack2(float a, float b) {
    return rne16(a) | (rne16(b) << 16);
}

// ---------------- fused cast x->bf16 + degree count ----------------
// grid = N_NODES*IN_C/4/256 = 6250 blocks; first 800k threads also count.
__global__ void cast_count(const float4* __restrict__ x, uint2* __restrict__ xb,
                           const int* __restrict__ nidx, const int* __restrict__ hidx,
                           int* __restrict__ cnt_n, int* __restrict__ cnt_h) {
    int i = blockIdx.x * 256 + threadIdx.x;
    float4 v = x[i];
    uint2 o;
    o.x = pack2(v.x, v.y);
    o.y = pack2(v.z, v.w);
    xb[i] = o;
    if (i < NNZ) {
        atomicAdd(&cnt_n[nidx[i]], 1);
        atomicAdd(&cnt_h[hidx[i]], 1);
    }
}

// ---------------- merged hierarchical exclusive scan ----------------
#define NB_N 49  // ceil(50000/1024)
#define NB_H 5   // ceil(5000/1024)

__global__ void scan1_both(const int* __restrict__ cnt_n, int* __restrict__ start_n,
                           int* __restrict__ part_n, const int* __restrict__ cnt_h,
                           int* __restrict__ start_h, int* __restrict__ part_h) {
    __shared__ int buf[256];
    int b = blockIdx.x, tid = threadIdx.x;
    const int* cnt; int* start; int* part; int n; int bb;
    if (b < NB_N) { cnt = cnt_n; start = start_n; part = part_n; n = N_NODES; bb = b; }
    else          { cnt = cnt_h; start = start_h; part = part_h; n = N_HEDGES; bb = b - NB_N; }
    int base = bb * 1024 + tid * 4;
    int v0 = (base + 0 < n) ? cnt[base + 0] : 0;
    int v1 = (base + 1 < n) ? cnt[base + 1] : 0;
    int v2 = (base + 2 < n) ? cnt[base + 2] : 0;
    int v3 = (base + 3 < n) ? cnt[base + 3] : 0;
    int tsum = v0 + v1 + v2 + v3;
    buf[tid] = tsum;
    __syncthreads();
    for (int off = 1; off < 256; off <<= 1) {
        int t = (tid >= off) ? buf[tid - off] : 0;
        __syncthreads();
        buf[tid] += t;
        __syncthreads();
    }
    int ex = buf[tid] - tsum;
    if (tid == 255) part[bb] = buf[255];
    if (base + 0 < n) start[base + 0] = ex;
    if (base + 1 < n) start[base + 1] = ex + v0;
    if (base + 2 < n) start[base + 2] = ex + v0 + v1;
    if (base + 3 < n) start[base + 3] = ex + v0 + v1 + v2;
}

// one block of 128: wave 0 scans part_n, wave 1 scans part_h (shuffle prefix)
__global__ void scan2_both(int* __restrict__ part_n, int* __restrict__ part_h) {
    int t = threadIdx.x;
    int w = t >> 6, lane = t & 63;
    int* p = w ? part_h : part_n;
    int nb = w ? NB_H : NB_N;
    int v = (lane < nb) ? p[lane] : 0;
    int s = v;
    for (int off = 1; off < 64; off <<= 1) {
        int y = __shfl_up(s, off);
        if (lane >= off) s += y;
    }
    if (lane < nb) p[lane] = s - v;  // exclusive
}

__global__ void scan3_both(int* __restrict__ start_n, const int* __restrict__ part_n,
                           int* __restrict__ start_h, const int* __restrict__ part_h) {
    int i = blockIdx.x * 256 + threadIdx.x;
    if (i < N_NODES) {
        start_n[i] += part_n[i >> 10];
        if (i == 0) start_n[N_NODES] = NNZ;
    } else if (i < N_NODES + N_HEDGES) {
        int k = i - N_NODES;
        start_h[k] += part_h[k >> 10];
        if (k == 0) start_h[N_HEDGES] = NNZ;
    }
}

// ---------------- fill adjacency lists (u16 entries) ----------------
__global__ void fill_adj(const int* __restrict__ nidx, const int* __restrict__ hidx,
                         const int* __restrict__ start_n, const int* __restrict__ start_h,
                         int* __restrict__ cur_n, int* __restrict__ cur_h,
                         u16* __restrict__ adj_n, u16* __restrict__ adj_h) {
    int i = blockIdx.x * 256 + threadIdx.x;
    if (i < NNZ) {
        int n = nidx[i], h = hidx[i];
        int pn = atomicAdd(&cur_n[n], 1);
        adj_n[start_n[n] + pn] = (u16)h;
        int ph = atomicAdd(&cur_h[h], 1);
        adj_h[start_h[h] + ph] = (u16)n;
    }
}

// ---------------- bf16-source pull-gather, fused 1/len (+bias+relu) ----------------
template <int F, bool BIAS_RELU, bool DST_BF16>
__global__ void gatherb(const uint4* __restrict__ src, const int* __restrict__ start,
                        const u16* __restrict__ adj, const float4* __restrict__ bias,
                        void* __restrict__ dst, int nrows) {
    constexpr int L = F / 8;
    int gid = blockIdx.x * 256 + threadIdx.x;
    int row = gid / L;
    if (row >= nrows) return;
    int c = gid - row * L;
    int s = start[row], e = start[row + 1];
    float a0[8] = {0, 0, 0, 0, 0, 0, 0, 0};
    float a1[8] = {0, 0, 0, 0, 0, 0, 0, 0};
    int j = s;
    for (; j + 1 < e; j += 2) {
        uint4 v0 = src[(int)adj[j] * L + c];
        uint4 v1 = src[(int)adj[j + 1] * L + c];
        a0[0] += bf_lo(v0.x); a0[1] += bf_hi(v0.x);
        a0[2] += bf_lo(v0.y); a0[3] += bf_hi(v0.y);
        a0[4] += bf_lo(v0.z); a0[5] += bf_hi(v0.z);
        a0[6] += bf_lo(v0.w); a0[7] += bf_hi(v0.w);
        a1[0] += bf_lo(v1.x); a1[1] += bf_hi(v1.x);
        a1[2] += bf_lo(v1.y); a1[3] += bf_hi(v1.y);
        a1[4] += bf_lo(v1.z); a1[5] += bf_hi(v1.z);
        a1[6] += bf_lo(v1.w); a1[7] += bf_hi(v1.w);
    }
    if (j < e) {
        uint4 v0 = src[(int)adj[j] * L + c];
        a0[0] += bf_lo(v0.x); a0[1] += bf_hi(v0.x);
        a0[2] += bf_lo(v0.y); a0[3] += bf_hi(v0.y);
        a0[4] += bf_lo(v0.z); a0[5] += bf_hi(v0.z);
        a0[6] += bf_lo(v0.w); a0[7] += bf_hi(v0.w);
    }
    float inv = (e > s) ? 1.f / (float)(e - s) : 0.f;
    float r[8];
#pragma unroll
    for (int t = 0; t < 8; t++) r[t] = (a0[t] + a1[t]) * inv;
    if (BIAS_RELU) {
        float4 b0 = bias[c * 2], b1v = bias[c * 2 + 1];
        r[0] = fmaxf(r[0] + b0.x, 0.f); r[1] = fmaxf(r[1] + b0.y, 0.f);
        r[2] = fmaxf(r[2] + b0.z, 0.f); r[3] = fmaxf(r[3] + b0.w, 0.f);
        r[4] = fmaxf(r[4] + b1v.x, 0.f); r[5] = fmaxf(r[5] + b1v.y, 0.f);
        r[6] = fmaxf(r[6] + b1v.z, 0.f); r[7] = fmaxf(r[7] + b1v.w, 0.f);
    }
    if (DST_BF16) {
        uint4 o;
        o.x = pack2(r[0], r[1]);
        o.y = pack2(r[2], r[3]);
        o.z = pack2(r[4], r[5]);
        o.w = pack2(r[6], r[7]);
        ((uint4*)dst)[row * L + c] = o;
    } else {
        float4* d = (float4*)dst;
        d[row * (F / 4) + c * 2]     = make_float4(r[0], r[1], r[2], r[3]);
        d[row * (F / 4) + c * 2 + 1] = make_float4(r[4], r[5], r[6], r[7]);
    }
}

// ---------------- f32 pull-gather (final), fused Dinv+bias+relu ----------------
template <int F, bool BIAS_RELU>
__global__ void gather4(const float4* __restrict__ src, const int* __restrict__ start,
                        const u16* __restrict__ adj, const float4* __restrict__ bias,
                        float4* __restrict__ dst) {
    constexpr int L = F / 4;
    int gid = blockIdx.x * 256 + threadIdx.x;
    int row = gid / L;
    int c = gid - row * L;
    int s = start[row], e = start[row + 1];
    float4 a0 = {0, 0, 0, 0}, a1 = {0, 0, 0, 0};
    int j = s;
    for (; j + 1 < e; j += 2) {
        float4 v0 = src[(int)adj[j] * L + c];
        float4 v1 = src[(int)adj[j + 1] * L + c];
        a0.x += v0.x; a0.y += v0.y; a0.z += v0.z; a0.w += v0.w;
        a1.x += v1.x; a1.y += v1.y; a1.z += v1.z; a1.w += v1.w;
    }
    if (j < e) {
        float4 v = src[(int)adj[j] * L + c];
        a0.x += v.x; a0.y += v.y; a0.z += v.z; a0.w += v.w;
    }
    float inv = (e > s) ? 1.f / (float)(e - s) : 0.f;
    float4 r;
    r.x = (a0.x + a1.x) * inv;
    r.y = (a0.y + a1.y) * inv;
    r.z = (a0.z + a1.z) * inv;
    r.w = (a0.w + a1.w) * inv;
    if (BIAS_RELU) {
        float4 bb = bias[c];
        r.x = fmaxf(r.x + bb.x, 0.f);
        r.y = fmaxf(r.y + bb.y, 0.f);
        r.z = fmaxf(r.z + bb.z, 0.f);
        r.w = fmaxf(r.w + bb.w, 0.f);
    }
    dst[row * L + c] = r;
}

// ---------------- e1 = aggx @ W1  [5000,128]@[128,256], bf16 out ----------------
__global__ void gemm1(const float* __restrict__ aggx, const float* __restrict__ W1,
                      u16* __restrict__ e1b) {
    __shared__ float a[4][IN_C];
    int h0 = blockIdx.x * 4;
    int tid = threadIdx.x;  // 256
    if (tid < 128) {
        float4 v = ((const float4*)aggx)[h0 * 32 + tid];
        int r = tid >> 5, k4 = (tid & 31) * 4;
        a[r][k4] = v.x; a[r][k4 + 1] = v.y; a[r][k4 + 2] = v.z; a[r][k4 + 3] = v.w;
    }
    __syncthreads();
    float acc0 = 0.f, acc1 = 0.f, acc2 = 0.f, acc3 = 0.f;
    for (int k = 0; k < IN_C; k++) {
        float w = W1[k * D1 + tid];
        acc0 += a[0][k] * w;
        acc1 += a[1][k] * w;
        acc2 += a[2][k] * w;
        acc3 += a[3][k] * w;
    }
    e1b[(h0 + 0) * D1 + tid] = (u16)rne16(acc0);
    e1b[(h0 + 1) * D1 + tid] = (u16)rne16(acc1);
    e1b[(h0 + 2) * D1 + tid] = (u16)rne16(acc2);
    e1b[(h0 + 3) * D1 + tid] = (u16)rne16(acc3);
}

// ---------------- fused: h = relu(Dinv*gather(e1b)+b1);  hw = h @ W2 (bf16) ----------------
// block = 256 threads = 8 node-rows x 32 lanes; grid = 50000/8 = 6250 blocks.
__global__ void gather_node_w2(const uint4* __restrict__ e1b, const int* __restrict__ start,
                               const u16* __restrict__ adj, const float4* __restrict__ b1,
                               const float* __restrict__ W2, u32* __restrict__ hw) {
    __shared__ float hs[8][D1];  // 8 KB
    int tid = threadIdx.x;
    int r = tid >> 5;       // row in block (0..7)
    int c = tid & 31;       // lane within row
    int node = blockIdx.x * 8 + r;
    int s = start[node], e = start[node + 1];
    float a0[8] = {0, 0, 0, 0, 0, 0, 0, 0};
    float a1[8] = {0, 0, 0, 0, 0, 0, 0, 0};
    int j = s;
    for (; j + 1 < e; j += 2) {
        uint4 v0 = e1b[(int)adj[j] * 32 + c];
        uint4 v1 = e1b[(int)adj[j + 1] * 32 + c];
        a0[0] += bf_lo(v0.x); a0[1] += bf_hi(v0.x);
        a0[2] += bf_lo(v0.y); a0[3] += bf_hi(v0.y);
        a0[4] += bf_lo(v0.z); a0[5] += bf_hi(v0.z);
        a0[6] += bf_lo(v0.w); a0[7] += bf_hi(v0.w);
        a1[0] += bf_lo(v1.x); a1[1] += bf_hi(v1.x);
        a1[2] += bf_lo(v1.y); a1[3] += bf_hi(v1.y);
        a1[4] += bf_lo(v1.z); a1[5] += bf_hi(v1.z);
        a1[6] += bf_lo(v1.w); a1[7] += bf_hi(v1.w);
    }
    if (j < e) {
        uint4 v0 = e1b[(int)adj[j] * 32 + c];
        a0[0] += bf_lo(v0.x); a0[1] += bf_hi(v0.x);
        a0[2] += bf_lo(v0.y); a0[3] += bf_hi(v0.y);
        a0[4] += bf_lo(v0.z); a0[5] += bf_hi(v0.z);
        a0[6] += bf_lo(v0.w); a0[7] += bf_hi(v0.w);
    }
    float inv = (e > s) ? 1.f / (float)(e - s) : 0.f;
    float4 bb0 = b1[c * 2], bb1 = b1[c * 2 + 1];
    float h0v = fmaxf((a0[0] + a1[0]) * inv + bb0.x, 0.f);
    float h1v = fmaxf((a0[1] + a1[1]) * inv + bb0.y, 0.f);
    float h2v = fmaxf((a0[2] + a1[2]) * inv + bb0.z, 0.f);
    float h3v = fmaxf((a0[3] + a1[3]) * inv + bb0.w, 0.f);
    float h4v = fmaxf((a0[4] + a1[4]) * inv + bb1.x, 0.f);
    float h5v = fmaxf((a0[5] + a1[5]) * inv + bb1.y, 0.f);
    float h6v = fmaxf((a0[6] + a1[6]) * inv + bb1.z, 0.f);
    float h7v = fmaxf((a0[7] + a1[7]) * inv + bb1.w, 0.f);
    int k0 = c * 8;
    hs[r][k0 + 0] = h0v; hs[r][k0 + 1] = h1v; hs[r][k0 + 2] = h2v; hs[r][k0 + 3] = h3v;
    hs[r][k0 + 4] = h4v; hs[r][k0 + 5] = h5v; hs[r][k0 + 6] = h6v; hs[r][k0 + 7] = h7v;
    __syncthreads();
    // hw[node, j0..j0+1] = sum_k hs[r][k] * W2[k][j0..j0+1]
    float acc0 = 0.f, acc1 = 0.f;
    const float2* W2v = (const float2*)W2;
#pragma unroll 4
    for (int k = 0; k < D1; k++) {
        float hv = hs[r][k];
        float2 w = W2v[k * 32 + c];
        acc0 += hv * w.x;
        acc1 += hv * w.y;
    }
    hw[node * 32 + c] = pack2(acc0, acc1);
}

extern "C" void kernel_launch(void* const* d_in, const int* in_sizes, int n_in,
                              void* d_out, int out_size, void* d_ws, size_t ws_size,
                              hipStream_t stream) {
    const float* x  = (const float*)d_in[0];
    const int* edge = (const int*)d_in[1];
    const int* nidx = edge;         // edge[0, :]
    const int* hidx = edge + NNZ;   // edge[1, :]
    const float* W1 = (const float*)d_in[2];
    const float* b1 = (const float*)d_in[3];
    const float* W2 = (const float*)d_in[4];
    const float* b2 = (const float*)d_in[5];
    float* out = (float*)d_out;

    // ---- workspace layout (all chunks 16B-aligned) ----
    float* aggx = (float*)d_ws;               // 5000*128 f32   = 640,000
    float* e2f  = aggx + N_HEDGES * IN_C;     // 5000*64  f32   = 320,000
    u16* xb     = (u16*)(e2f + N_HEDGES * D2);// 50000*128 u16  = 6,400,000
    u16* e1b    = xb + N_NODES * IN_C;        // 5000*256  u16  = 1,280,000
    u32* hw     = (u32*)(e1b + N_HEDGES * D1);// 50000*32  u32  = 1,600,000 (64 bf16/row)
    int* cnt_n  = (int*)(hw + N_NODES * 32);  // 50000 (zeroed)
    int* cnt_h  = cnt_n + N_NODES;            // 5000  (zeroed)
    int* cur_n  = cnt_h + N_HEDGES;           // 50000 (zeroed)
    int* cur_h  = cur_n + N_NODES;            // 5000  (zeroed)
    size_t zero_ints = 2 * (N_NODES + N_HEDGES);
    int* start_n = cur_h + N_HEDGES;          // 50001
    int* start_h = start_n + (N_NODES + 1);   // 5001
    int* part_n  = start_h + (N_HEDGES + 1);  // 64
    int* part_h  = part_n + 64;               // 64
    u16* adj_n   = (u16*)(part_h + 64);       // 800000 u16
    u16* adj_h   = adj_n + NNZ;               // 800000 u16
    // total ≈ 3.8 MB f32 + 21.8 MB u16/u32 + ints ≈ 30 MB

    hipMemsetAsync(cnt_n, 0, zero_ints * sizeof(int), stream);

    cast_count<<<N_NODES * IN_C / 4 / 256, 256, 0, stream>>>(
        (const float4*)x, (uint2*)xb, nidx, hidx, cnt_n, cnt_h);

    scan1_both<<<NB_N + NB_H, 256, 0, stream>>>(cnt_n, start_n, part_n,
                                                cnt_h, start_h, part_h);
    scan2_both<<<1, 128, 0, stream>>>(part_n, part_h);
    scan3_both<<<(N_NODES + N_HEDGES + 255) / 256, 256, 0, stream>>>(
        start_n, part_n, start_h, part_h);

    fill_adj<<<(NNZ + 255) / 256, 256, 0, stream>>>(nidx, hidx, start_n, start_h,
                                                    cur_n, cur_h, adj_n, adj_h);

    // layer 1: aggx = Binv * gather(xb);  e1b = aggx @ W1 (bf16)
    gatherb<IN_C, false, false><<<(N_HEDGES * (IN_C / 8) + 255) / 256, 256, 0, stream>>>(
        (const uint4*)xb, start_h, adj_h, nullptr, aggx, N_HEDGES);
    gemm1<<<N_HEDGES / 4, 256, 0, stream>>>(aggx, W1, e1b);

    // fused: h = relu(Dinv*gather(e1b)+b1); hw = h @ W2
    gather_node_w2<<<N_NODES / 8, 256, 0, stream>>>(
        (const uint4*)e1b, start_n, adj_n, (const float4*)b1, W2, hw);

    // layer 2: e2f = Binv * gather(hw); out = relu(Dinv*gather(e2f)+b2)
    gatherb<D2, false, false><<<(N_HEDGES * (D2 / 8) + 255) / 256, 256, 0, stream>>>(
        (const uint4*)hw, start_h, adj_h, nullptr, e2f, N_HEDGES);
    gather4<D2, true><<<N_NODES * (D2 / 4) / 256, 256, 0, stream>>>(
        (const float4*)e2f, start_n, adj_n, (const float4*)b2, (float4*)out);
}

// Round 6
// 449.636 us; speedup vs baseline: 1.3595x; 1.3595x over previous
//
#include <hip/hip_runtime.h>

#define N_NODES 50000
#define N_HEDGES 5000
#define NNZ 800000
#define IN_C 128
#define D1 256
#define D2 64

typedef unsigned int u32;
typedef unsigned short u16;

// ---- bf16 helpers: storage bf16, math f32 ----
__device__ __forceinline__ float bf_lo(u32 u) { return __uint_as_float(u << 16); }
__device__ __forceinline__ float bf_hi(u32 u) { return __uint_as_float(u & 0xffff0000u); }
__device__ __forceinline__ u32 rne16(float f) {
    u32 u = __float_as_uint(f);
    return (u + 0x7fffu + ((u >> 16) & 1u)) >> 16;
}
__device__ __forceinline__ u32 pack2(float a, float b) {
    return rne16(a) | (rne16(b) << 16);
}

// ---------------- fused cast x->bf16 + degree count ----------------
__global__ void cast_count(const float4* __restrict__ x, uint2* __restrict__ xb,
                           const int* __restrict__ nidx, const int* __restrict__ hidx,
                           int* __restrict__ cnt_n, int* __restrict__ cnt_h) {
    int i = blockIdx.x * 256 + threadIdx.x;
    float4 v = x[i];
    uint2 o;
    o.x = pack2(v.x, v.y);
    o.y = pack2(v.z, v.w);
    xb[i] = o;
    if (i < NNZ) {
        atomicAdd(&cnt_n[nidx[i]], 1);
        atomicAdd(&cnt_h[hidx[i]], 1);
    }
}

// ---------------- merged hierarchical exclusive scan ----------------
#define NB_N 49  // ceil(50000/1024)
#define NB_H 5   // ceil(5000/1024)

__global__ void scan1_both(const int* __restrict__ cnt_n, int* __restrict__ start_n,
                           int* __restrict__ part_n, const int* __restrict__ cnt_h,
                           int* __restrict__ start_h, int* __restrict__ part_h) {
    __shared__ int buf[256];
    int b = blockIdx.x, tid = threadIdx.x;
    const int* cnt; int* start; int* part; int n; int bb;
    if (b < NB_N) { cnt = cnt_n; start = start_n; part = part_n; n = N_NODES; bb = b; }
    else          { cnt = cnt_h; start = start_h; part = part_h; n = N_HEDGES; bb = b - NB_N; }
    int base = bb * 1024 + tid * 4;
    int v0 = (base + 0 < n) ? cnt[base + 0] : 0;
    int v1 = (base + 1 < n) ? cnt[base + 1] : 0;
    int v2 = (base + 2 < n) ? cnt[base + 2] : 0;
    int v3 = (base + 3 < n) ? cnt[base + 3] : 0;
    int tsum = v0 + v1 + v2 + v3;
    buf[tid] = tsum;
    __syncthreads();
    for (int off = 1; off < 256; off <<= 1) {
        int t = (tid >= off) ? buf[tid - off] : 0;
        __syncthreads();
        buf[tid] += t;
        __syncthreads();
    }
    int ex = buf[tid] - tsum;
    if (tid == 255) part[bb] = buf[255];
    if (base + 0 < n) start[base + 0] = ex;
    if (base + 1 < n) start[base + 1] = ex + v0;
    if (base + 2 < n) start[base + 2] = ex + v0 + v1;
    if (base + 3 < n) start[base + 3] = ex + v0 + v1 + v2;
}

__global__ void scan2_both(int* __restrict__ part_n, int* __restrict__ part_h) {
    int t = threadIdx.x;
    int w = t >> 6, lane = t & 63;
    int* p = w ? part_h : part_n;
    int nb = w ? NB_H : NB_N;
    int v = (lane < nb) ? p[lane] : 0;
    int s = v;
    for (int off = 1; off < 64; off <<= 1) {
        int y = __shfl_up(s, off);
        if (lane >= off) s += y;
    }
    if (lane < nb) p[lane] = s - v;  // exclusive
}

__global__ void scan3_both(int* __restrict__ start_n, const int* __restrict__ part_n,
                           int* __restrict__ start_h, const int* __restrict__ part_h) {
    int i = blockIdx.x * 256 + threadIdx.x;
    if (i < N_NODES) {
        start_n[i] += part_n[i >> 10];
        if (i == 0) start_n[N_NODES] = NNZ;
    } else if (i < N_NODES + N_HEDGES) {
        int k = i - N_NODES;
        start_h[k] += part_h[k >> 10];
        if (k == 0) start_h[N_HEDGES] = NNZ;
    }
}

// ---------------- fill adjacency lists (u16 entries) ----------------
__global__ void fill_adj(const int* __restrict__ nidx, const int* __restrict__ hidx,
                         const int* __restrict__ start_n, const int* __restrict__ start_h,
                         int* __restrict__ cur_n, int* __restrict__ cur_h,
                         u16* __restrict__ adj_n, u16* __restrict__ adj_h) {
    int i = blockIdx.x * 256 + threadIdx.x;
    if (i < NNZ) {
        int n = nidx[i], h = hidx[i];
        int pn = atomicAdd(&cur_n[n], 1);
        adj_n[start_n[n] + pn] = (u16)h;
        int ph = atomicAdd(&cur_h[h], 1);
        adj_h[start_h[h] + ph] = (u16)n;
    }
}

// ---------------- bf16-source pull-gather, fused 1/len (+bias+relu) ----------------
// F floats per row; L = F/8 lanes per row; each lane loads uint4 = 8 bf16.
template <int F, bool BIAS_RELU, bool DST_BF16>
__global__ void gatherb(const uint4* __restrict__ src, const int* __restrict__ start,
                        const u16* __restrict__ adj, const float4* __restrict__ bias,
                        void* __restrict__ dst, int nrows) {
    constexpr int L = F / 8;
    int gid = blockIdx.x * 256 + threadIdx.x;
    int row = gid / L;
    if (row >= nrows) return;
    int c = gid - row * L;
    int s = start[row], e = start[row + 1];
    float a0[8] = {0, 0, 0, 0, 0, 0, 0, 0};
    float a1[8] = {0, 0, 0, 0, 0, 0, 0, 0};
    int j = s;
    for (; j + 1 < e; j += 2) {
        uint4 v0 = src[(int)adj[j] * L + c];
        uint4 v1 = src[(int)adj[j + 1] * L + c];
        a0[0] += bf_lo(v0.x); a0[1] += bf_hi(v0.x);
        a0[2] += bf_lo(v0.y); a0[3] += bf_hi(v0.y);
        a0[4] += bf_lo(v0.z); a0[5] += bf_hi(v0.z);
        a0[6] += bf_lo(v0.w); a0[7] += bf_hi(v0.w);
        a1[0] += bf_lo(v1.x); a1[1] += bf_hi(v1.x);
        a1[2] += bf_lo(v1.y); a1[3] += bf_hi(v1.y);
        a1[4] += bf_lo(v1.z); a1[5] += bf_hi(v1.z);
        a1[6] += bf_lo(v1.w); a1[7] += bf_hi(v1.w);
    }
    if (j < e) {
        uint4 v0 = src[(int)adj[j] * L + c];
        a0[0] += bf_lo(v0.x); a0[1] += bf_hi(v0.x);
        a0[2] += bf_lo(v0.y); a0[3] += bf_hi(v0.y);
        a0[4] += bf_lo(v0.z); a0[5] += bf_hi(v0.z);
        a0[6] += bf_lo(v0.w); a0[7] += bf_hi(v0.w);
    }
    float inv = (e > s) ? 1.f / (float)(e - s) : 0.f;
    float r[8];
#pragma unroll
    for (int t = 0; t < 8; t++) r[t] = (a0[t] + a1[t]) * inv;
    if (BIAS_RELU) {
        float4 b0 = bias[c * 2], b1v = bias[c * 2 + 1];
        r[0] = fmaxf(r[0] + b0.x, 0.f); r[1] = fmaxf(r[1] + b0.y, 0.f);
        r[2] = fmaxf(r[2] + b0.z, 0.f); r[3] = fmaxf(r[3] + b0.w, 0.f);
        r[4] = fmaxf(r[4] + b1v.x, 0.f); r[5] = fmaxf(r[5] + b1v.y, 0.f);
        r[6] = fmaxf(r[6] + b1v.z, 0.f); r[7] = fmaxf(r[7] + b1v.w, 0.f);
    }
    if (DST_BF16) {
        uint4 o;
        o.x = pack2(r[0], r[1]);
        o.y = pack2(r[2], r[3]);
        o.z = pack2(r[4], r[5]);
        o.w = pack2(r[6], r[7]);
        ((uint4*)dst)[row * L + c] = o;
    } else {
        float4* d = (float4*)dst;
        d[row * (F / 4) + c * 2]     = make_float4(r[0], r[1], r[2], r[3]);
        d[row * (F / 4) + c * 2 + 1] = make_float4(r[4], r[5], r[6], r[7]);
    }
}

// ---------------- f32 pull-gather (final), fused Dinv+bias+relu ----------------
template <int F, bool BIAS_RELU>
__global__ void gather4(const float4* __restrict__ src, const int* __restrict__ start,
                        const u16* __restrict__ adj, const float4* __restrict__ bias,
                        float4* __restrict__ dst) {
    constexpr int L = F / 4;
    int gid = blockIdx.x * 256 + threadIdx.x;
    int row = gid / L;
    int c = gid - row * L;
    int s = start[row], e = start[row + 1];
    float4 a0 = {0, 0, 0, 0}, a1 = {0, 0, 0, 0};
    int j = s;
    for (; j + 1 < e; j += 2) {
        float4 v0 = src[(int)adj[j] * L + c];
        float4 v1 = src[(int)adj[j + 1] * L + c];
        a0.x += v0.x; a0.y += v0.y; a0.z += v0.z; a0.w += v0.w;
        a1.x += v1.x; a1.y += v1.y; a1.z += v1.z; a1.w += v1.w;
    }
    if (j < e) {
        float4 v = src[(int)adj[j] * L + c];
        a0.x += v.x; a0.y += v.y; a0.z += v.z; a0.w += v.w;
    }
    float inv = (e > s) ? 1.f / (float)(e - s) : 0.f;
    float4 r;
    r.x = (a0.x + a1.x) * inv;
    r.y = (a0.y + a1.y) * inv;
    r.z = (a0.z + a1.z) * inv;
    r.w = (a0.w + a1.w) * inv;
    if (BIAS_RELU) {
        float4 bb = bias[c];
        r.x = fmaxf(r.x + bb.x, 0.f);
        r.y = fmaxf(r.y + bb.y, 0.f);
        r.z = fmaxf(r.z + bb.z, 0.f);
        r.w = fmaxf(r.w + bb.w, 0.f);
    }
    dst[row * L + c] = r;
}

// ---------------- e1 = aggx @ W1  [5000,128]@[128,256], bf16 out ----------------
__global__ void gemm1(const float* __restrict__ aggx, const float* __restrict__ W1,
                      u16* __restrict__ e1b) {
    __shared__ float a[4][IN_C];
    int h0 = blockIdx.x * 4;
    int tid = threadIdx.x;  // 256
    if (tid < 128) {
        float4 v = ((const float4*)aggx)[h0 * 32 + tid];
        int r = tid >> 5, k4 = (tid & 31) * 4;
        a[r][k4] = v.x; a[r][k4 + 1] = v.y; a[r][k4 + 2] = v.z; a[r][k4 + 3] = v.w;
    }
    __syncthreads();
    float acc0 = 0.f, acc1 = 0.f, acc2 = 0.f, acc3 = 0.f;
    for (int k = 0; k < IN_C; k++) {
        float w = W1[k * D1 + tid];
        acc0 += a[0][k] * w;
        acc1 += a[1][k] * w;
        acc2 += a[2][k] * w;
        acc3 += a[3][k] * w;
    }
    e1b[(h0 + 0) * D1 + tid] = (u16)rne16(acc0);
    e1b[(h0 + 1) * D1 + tid] = (u16)rne16(acc1);
    e1b[(h0 + 2) * D1 + tid] = (u16)rne16(acc2);
    e1b[(h0 + 3) * D1 + tid] = (u16)rne16(acc3);
}

// ---------------- e2 = aggh @ W2  [5000,256]@[256,64] ----------------
__global__ void gemm2(const float* __restrict__ aggh, const float* __restrict__ W2,
                      float* __restrict__ e2) {
    __shared__ float a[4][D1];
    int h0 = blockIdx.x * 4;
    int tid = threadIdx.x;  // 256
    {
        float4 v = ((const float4*)aggh)[h0 * 64 + tid];
        int r = tid >> 6, k4 = (tid & 63) * 4;
        a[r][k4] = v.x; a[r][k4 + 1] = v.y; a[r][k4 + 2] = v.z; a[r][k4 + 3] = v.w;
    }
    __syncthreads();
    int r = tid >> 6, jj = tid & 63;
    float acc = 0.f;
    for (int k = 0; k < D1; k++) acc += a[r][k] * W2[k * D2 + jj];
    e2[(h0 + r) * D2 + jj] = acc;
}

extern "C" void kernel_launch(void* const* d_in, const int* in_sizes, int n_in,
                              void* d_out, int out_size, void* d_ws, size_t ws_size,
                              hipStream_t stream) {
    const float* x  = (const float*)d_in[0];
    const int* edge = (const int*)d_in[1];
    const int* nidx = edge;         // edge[0, :]
    const int* hidx = edge + NNZ;   // edge[1, :]
    const float* W1 = (const float*)d_in[2];
    const float* b1 = (const float*)d_in[3];
    const float* W2 = (const float*)d_in[4];
    const float* b2 = (const float*)d_in[5];
    float* out = (float*)d_out;

    // ---- workspace layout (all chunks 16B-aligned) ----
    float* aggx = (float*)d_ws;               // 5000*128 f32   = 640,000
    float* aggh = aggx + N_HEDGES * IN_C;     // 5000*256 f32   = 1,280,000
    float* e2f  = aggh + N_HEDGES * D1;       // 5000*64  f32   = 320,000
    u16* xb     = (u16*)(e2f + N_HEDGES * D2);// 50000*128 u16  = 6,400,000
    u16* e1b    = xb + N_NODES * IN_C;        // 5000*256  u16  = 1,280,000
    u16* hb     = e1b + N_HEDGES * D1;        // 50000*256 u16  = 12,800,000
    int* cnt_n  = (int*)(hb + N_NODES * D1);  // 50000 (zeroed)
    int* cnt_h  = cnt_n + N_NODES;            // 5000  (zeroed)
    int* cur_n  = cnt_h + N_HEDGES;           // 50000 (zeroed)
    int* cur_h  = cur_n + N_NODES;            // 5000  (zeroed)
    size_t zero_ints = 2 * (N_NODES + N_HEDGES);
    int* start_n = cur_h + N_HEDGES;          // 50001
    int* start_h = start_n + (N_NODES + 1);   // 5001
    int* part_n  = start_h + (N_HEDGES + 1);  // 64
    int* part_h  = part_n + 64;               // 64
    u16* adj_n   = (u16*)(part_h + 64);       // 800000 u16
    u16* adj_h   = adj_n + NNZ;               // 800000 u16
    // total ≈ 9 MB f32 + 41 MB u16 + 3.5 MB ≈ 53 MB

    hipMemsetAsync(cnt_n, 0, zero_ints * sizeof(int), stream);

    cast_count<<<N_NODES * IN_C / 4 / 256, 256, 0, stream>>>(
        (const float4*)x, (uint2*)xb, nidx, hidx, cnt_n, cnt_h);

    scan1_both<<<NB_N + NB_H, 256, 0, stream>>>(cnt_n, start_n, part_n,
                                                cnt_h, start_h, part_h);
    scan2_both<<<1, 128, 0, stream>>>(part_n, part_h);
    scan3_both<<<(N_NODES + N_HEDGES + 255) / 256, 256, 0, stream>>>(
        start_n, part_n, start_h, part_h);

    fill_adj<<<(NNZ + 255) / 256, 256, 0, stream>>>(nidx, hidx, start_n, start_h,
                                                    cur_n, cur_h, adj_n, adj_h);

    // layer 1: aggx = Binv * gather(xb);  e1b = aggx @ W1 (bf16)
    gatherb<IN_C, false, false><<<(N_HEDGES * (IN_C / 8) + 255) / 256, 256, 0, stream>>>(
        (const uint4*)xb, start_h, adj_h, nullptr, aggx, N_HEDGES);
    gemm1<<<N_HEDGES / 4, 256, 0, stream>>>(aggx, W1, e1b);
    // h = relu(Dinv*gather(e1b)+b1) -> hb (bf16)
    gatherb<D1, true, true><<<N_NODES * (D1 / 8) / 256, 256, 0, stream>>>(
        (const uint4*)e1b, start_n, adj_n, (const float4*)b1, hb, N_NODES);

    // layer 2: aggh = Binv * gather(hb);  e2 = aggh @ W2; out = relu(Dinv*gather(e2)+b2)
    gatherb<D1, false, false><<<N_HEDGES * (D1 / 8) / 256, 256, 0, stream>>>(
        (const uint4*)hb, start_h, adj_h, nullptr, aggh, N_HEDGES);
    gemm2<<<N_HEDGES / 4, 256, 0, stream>>>(aggh, W2, e2f);
    gather4<D2, true><<<N_NODES * (D2 / 4) / 256, 256, 0, stream>>>(
        (const float4*)e2f, start_n, adj_n, (const float4*)b2, (float4*)out);
}